// Round 6
// baseline (228.902 us; speedup 1.0000x reference)
//
#include <hip/hip_runtime.h>

typedef unsigned short u16;
typedef __attribute__((ext_vector_type(8))) short short8;
typedef __attribute__((ext_vector_type(4))) float f32x4;

// ---------- helpers ----------

__device__ __forceinline__ u16 f2bf(float f) {
  unsigned u = __builtin_bit_cast(unsigned, f);
  u += 0x7fffu + ((u >> 16) & 1u);   // RNE
  return (u16)(u >> 16);
}

__device__ __forceinline__ void gload16(const void* g, void* l) {
  __builtin_amdgcn_global_load_lds(
      (const __attribute__((address_space(1))) unsigned*)g,
      (__attribute__((address_space(3))) unsigned*)l, 16, 0, 0);
}

#define MFMA16(a, b, c) __builtin_amdgcn_mfma_f32_16x16x32_bf16(a, b, c, 0, 0, 0)

// ================================================================
// 256x128 GEMM core, 512 threads / 8 waves, 4 m201-style phases/tile.
// Waves 4(M)x2(N), each owns 64x64 -> acc[4][4]. K = ntiles*64, ntiles>=2.
// LDS: 3 K-tile buffers of (A 256x64 + B 128x64) bf16 = 48 KB each,
// 16B-chunk XOR swizzle, dist-2 prefetch, vmcnt(2) once per tile (never 0
// in the staged loop). Per phase: {ds_reads | 2 gloads | bar | lgkm(0) |
// setprio(1) 8 MFMA setprio(0) | bar} — small read bursts interleave with
// MFMA clusters across waves (m201/m196 mechanism). lgkm(0) per phase ->
// no read-order hazards. Tile t reads ONLY slot t%3; stage writes slot
// (t+2)%3; slot t+1 untouched during t -> race-free by construction.
// Sync ledger: tile t's 6 loads complete at tile t-1 ph0's vmcnt(2) and
// become visible at the barrier right after; slot (t+2)%3 ≡ (t-1)%3 is
// only gload-written after tile t-1 ph3's end barrier, by which point all
// waves' reads of it are lgkm-drained.
// ================================================================

#define TILE4(DOSTAGE, VM)                                                    \
  {                                                                           \
    char* cA = sA0 + cur * 49152;                                             \
    char* cB = cA + 32768;                                                    \
    char* sD = sA0 + ((cur + 2 >= 3) ? (cur - 1) : (cur + 2)) * 49152;        \
    /* ---- phase 0: B kk0 (4r) + A rows 0-31 kk0 (2r); stage A 1-2 ---- */   \
    _Pragma("unroll") for (int j = 0; j < 4; ++j) {                           \
      const int rn = wc + j * 16 + l16;                                       \
      bfr[0][j] = *(const short8*)(cB + rn * 128 + ((quad ^ (rn & 7)) * 16)); \
    }                                                                         \
    _Pragma("unroll") for (int i = 0; i < 2; ++i) {                           \
      const int rm = wr + i * 16 + l16;                                       \
      af0[i] = *(const short8*)(cA + rm * 128 + ((quad ^ (rm & 7)) * 16));    \
    }                                                                         \
    if (DOSTAGE) {                                                            \
      gload16(ga[0], sD + la[0]); ga[0] += 64;                                \
      gload16(ga[1], sD + la[1]); ga[1] += 64;                                \
    }                                                                         \
    asm volatile("s_waitcnt vmcnt(" VM ")" ::: "memory");                     \
    __builtin_amdgcn_s_barrier();                                             \
    asm volatile("s_waitcnt lgkmcnt(0)" ::: "memory");                        \
    __builtin_amdgcn_sched_barrier(0);                                        \
    __builtin_amdgcn_s_setprio(1);                                            \
    _Pragma("unroll") for (int i = 0; i < 2; ++i)                             \
      _Pragma("unroll") for (int j = 0; j < 4; ++j)                           \
        acc[i][j] = MFMA16(af0[i], bfr[0][j], acc[i][j]);                     \
    __builtin_amdgcn_s_setprio(0);                                            \
    asm volatile("" ::: "memory");                                            \
    __builtin_amdgcn_s_barrier();                                             \
    asm volatile("" ::: "memory");                                            \
    /* ---- phase 1: B kk1 (4r) + A rows 0-31 kk1 (2r); stage A 3-4 ---- */   \
    _Pragma("unroll") for (int j = 0; j < 4; ++j) {                           \
      const int rn = wc + j * 16 + l16;                                       \
      bfr[1][j] = *(const short8*)(cB + rn * 128 + (((4 + quad) ^ (rn & 7)) * 16)); \
    }                                                                         \
    _Pragma("unroll") for (int i = 0; i < 2; ++i) {                           \
      const int rm = wr + i * 16 + l16;                                       \
      af1[i] = *(const short8*)(cA + rm * 128 + (((4 + quad) ^ (rm & 7)) * 16)); \
    }                                                                         \
    if (DOSTAGE) {                                                            \
      gload16(ga[2], sD + la[2]); ga[2] += 64;                                \
      gload16(ga[3], sD + la[3]); ga[3] += 64;                                \
    }                                                                         \
    __builtin_amdgcn_s_barrier();                                             \
    asm volatile("s_waitcnt lgkmcnt(0)" ::: "memory");                        \
    __builtin_amdgcn_sched_barrier(0);                                        \
    __builtin_amdgcn_s_setprio(1);                                            \
    _Pragma("unroll") for (int i = 0; i < 2; ++i)                             \
      _Pragma("unroll") for (int j = 0; j < 4; ++j)                           \
        acc[i][j] = MFMA16(af1[i], bfr[1][j], acc[i][j]);                     \
    __builtin_amdgcn_s_setprio(0);                                            \
    asm volatile("" ::: "memory");                                            \
    __builtin_amdgcn_s_barrier();                                             \
    asm volatile("" ::: "memory");                                            \
    /* ---- phase 2: A rows 32-63 kk0 (2r); stage B 5-6 (B region!) ---- */   \
    _Pragma("unroll") for (int i = 0; i < 2; ++i) {                           \
      const int rm = wr + 32 + i * 16 + l16;                                  \
      af0[i] = *(const short8*)(cA + rm * 128 + ((quad ^ (rm & 7)) * 16));    \
    }                                                                         \
    if (DOSTAGE) {                                                            \
      gload16(gb[0], sD + 32768 + lb[0]); gb[0] += 64;                        \
      gload16(gb[1], sD + 32768 + lb[1]); gb[1] += 64;                        \
    }                                                                         \
    __builtin_amdgcn_s_barrier();                                             \
    asm volatile("s_waitcnt lgkmcnt(0)" ::: "memory");                        \
    __builtin_amdgcn_sched_barrier(0);                                        \
    __builtin_amdgcn_s_setprio(1);                                            \
    _Pragma("unroll") for (int i = 0; i < 2; ++i)                             \
      _Pragma("unroll") for (int j = 0; j < 4; ++j)                           \
        acc[2 + i][j] = MFMA16(af0[i], bfr[0][j], acc[2 + i][j]);             \
    __builtin_amdgcn_s_setprio(0);                                            \
    asm volatile("" ::: "memory");                                            \
    __builtin_amdgcn_s_barrier();                                             \
    asm volatile("" ::: "memory");                                            \
    /* ---- phase 3: A rows 32-63 kk1 (2r) ---- */                            \
    _Pragma("unroll") for (int i = 0; i < 2; ++i) {                           \
      const int rm = wr + 32 + i * 16 + l16;                                  \
      af1[i] = *(const short8*)(cA + rm * 128 + (((4 + quad) ^ (rm & 7)) * 16)); \
    }                                                                         \
    __builtin_amdgcn_s_barrier();                                             \
    asm volatile("s_waitcnt lgkmcnt(0)" ::: "memory");                        \
    __builtin_amdgcn_sched_barrier(0);                                        \
    __builtin_amdgcn_s_setprio(1);                                            \
    _Pragma("unroll") for (int i = 0; i < 2; ++i)                             \
      _Pragma("unroll") for (int j = 0; j < 4; ++j)                           \
        acc[2 + i][j] = MFMA16(af1[i], bfr[1][j], acc[2 + i][j]);             \
    __builtin_amdgcn_s_setprio(0);                                            \
    asm volatile("" ::: "memory");                                            \
    __builtin_amdgcn_s_barrier();                                             \
    asm volatile("" ::: "memory");                                            \
    cur = (cur + 1 >= 3) ? 0 : cur + 1;                                       \
  }

__device__ __forceinline__ void gemm_256x128(
    const u16* __restrict__ A, const u16* __restrict__ B,
    int m0, int n0, int ntiles, char* smem, f32x4 acc[4][4])
{
  const int tid  = threadIdx.x;          // 0..511
  const int lane = tid & 63;
  const int quad = lane >> 4;
  const int l16  = lane & 15;
  const int wave = tid >> 6;             // 0..7
  const int wr   = (wave >> 1) << 6;     // 0,64,128,192
  const int wc   = (wave & 1) << 6;      // 0,64

  // staging sources (pre-swizzled global addr, linear LDS dest)
  const u16* ga[4]; int la[4];
  const u16* gb[2]; int lb[2];
#pragma unroll
  for (int j = 0; j < 4; ++j) {
    const int L = j * 512 + tid;         // 2048 chunks: 256 rows x 8
    const int r = L >> 3;
    const int c = (L & 7) ^ (r & 7);
    la[j] = L * 16;
    ga[j] = A + (size_t)(m0 + r) * 1024 + c * 8;
  }
#pragma unroll
  for (int j = 0; j < 2; ++j) {
    const int L = j * 512 + tid;         // 1024 chunks: 128 rows x 8
    const int r = L >> 3;
    const int c = (L & 7) ^ (r & 7);
    lb[j] = L * 16;
    gb[j] = B + (size_t)(n0 + r) * 1024 + c * 8;
  }
  char* const sA0 = smem;                // slot s: A at s*49152, B at +32768

  short8 bfr[2][4];                      // B frags (kk x j), held ph0->ph3
  short8 af0[2], af1[2];                 // A frags, phase-alternating

  // prologue: stage tiles 0 and 1 (6 gloads each)
  {
    char* dA = sA0; char* dB = sA0 + 32768;
#pragma unroll
    for (int j = 0; j < 4; ++j) { gload16(ga[j], dA + la[j]); ga[j] += 64; }
#pragma unroll
    for (int j = 0; j < 2; ++j) { gload16(gb[j], dB + lb[j]); gb[j] += 64; }
    dA = sA0 + 49152; dB = dA + 32768;
#pragma unroll
    for (int j = 0; j < 4; ++j) { gload16(ga[j], dA + la[j]); ga[j] += 64; }
#pragma unroll
    for (int j = 0; j < 2; ++j) { gload16(gb[j], dB + lb[j]); gb[j] += 64; }
  }
  asm volatile("s_waitcnt vmcnt(6)" ::: "memory");   // tile0 done, tile1 in flight
  __builtin_amdgcn_s_barrier();
  asm volatile("" ::: "memory");

  int cur = 0;
#pragma unroll 1
  for (int t = 0; t < ntiles - 2; ++t) { // staged tiles (stage t+2)
    TILE4(true, "2");
  }
  TILE4(false, "0");                     // tile nt-2: drain last tile's loads
  TILE4(false, "0");                     // tile nt-1
  __syncthreads();                       // epilogue may rewrite LDS
}

#define ACC_ZERO4(acc) { _Pragma("unroll") for (int i=0;i<4;++i) \
  _Pragma("unroll") for (int j=0;j<4;++j) \
  _Pragma("unroll") for (int r=0;r<4;++r) acc[i][j][r]=0.f; }

// ---------- epilogue: 256x128 acc(+bias) -> bf16 C via LDS repack ----------
__device__ __forceinline__ void store256x128_bf16(
    f32x4 acc[4][4], const float* bias, int n0,
    u16* C, int m0, char* smem)
{
  const int tid = threadIdx.x, lane = tid & 63, wave = tid >> 6;
  const int quad = lane >> 4, l16 = lane & 15;
  const int wr = (wave >> 1) << 6, wc = (wave & 1) << 6;
  u16* t = (u16*)smem;                       // 256 x 136 u16
#pragma unroll
  for (int j = 0; j < 4; ++j) {
    const int nn = wc + j * 16 + l16;
    const float bj = bias[n0 + nn];
#pragma unroll
    for (int i = 0; i < 4; ++i) {
      const int mm = wr + i * 16 + quad * 4;
#pragma unroll
      for (int r = 0; r < 4; ++r)
        t[(mm + r) * 136 + nn] = f2bf(acc[i][j][r] + bj);
    }
  }
  __syncthreads();
#pragma unroll
  for (int it = 0; it < 8; ++it) {
    const int L = it * 512 + tid;              // 4096 chunks of 8 u16
    const int mm = L >> 4, cc = L & 15;
    *(uint4*)(C + (size_t)(m0 + mm) * 1024 + n0 + cc * 8) =
        *(const uint4*)(t + mm * 136 + cc * 8);
  }
}

// ---------- kernel 1: cast fp32 -> bf16 (x + 4 weights) + zero rowsum ----------
__global__ __launch_bounds__(256) void cast_inputs(
    const float* __restrict__ x,  const float* __restrict__ wq,
    const float* __restrict__ wk, const float* __restrict__ wv,
    const float* __restrict__ wo,
    u16* xb, u16* wqb, u16* wkb, u16* wvb, u16* wob, float* rsum)
{
  int b = blockIdx.x;
  if (b < 8) {                               // fold rowsum zeroing (8192 floats)
    float4 z = {0.f, 0.f, 0.f, 0.f};
    *(float4*)(rsum + (b * 256 + threadIdx.x) * 4) = z;
  }
  const float* src; u16* dst; int base;
  if (b < 4096) { src = x; dst = xb; base = b * 2048; }
  else {
    int r = (b - 4096) >> 9, bb = (b - 4096) & 511;
    base = bb * 2048;
    src = (r == 0) ? wq : (r == 1) ? wk : (r == 2) ? wv : wo;
    dst = (r == 0) ? wqb : (r == 1) ? wkb : (r == 2) ? wvb : wob;
  }
  int i0 = base + threadIdx.x * 8;
  float4 f0 = *(const float4*)(src + i0);
  float4 f1 = *(const float4*)(src + i0 + 4);
  short8 o;
  o[0]=(short)f2bf(f0.x); o[1]=(short)f2bf(f0.y); o[2]=(short)f2bf(f0.z); o[3]=(short)f2bf(f0.w);
  o[4]=(short)f2bf(f1.x); o[5]=(short)f2bf(f1.y); o[6]=(short)f2bf(f1.z); o[7]=(short)f2bf(f1.w);
  *(short8*)(dst + i0) = o;
}

// ---------- kernel 2: fused QKV projection, 4-phase 256x128 core ----------
// grid (256, 3): x = XCD-chunked tile id, y = which weight (q/k/v).
__global__ __launch_bounds__(512, 2) void proj_qkv(
    const u16* __restrict__ xb,
    const u16* __restrict__ wqb, const u16* __restrict__ wkb, const u16* __restrict__ wvb,
    const float* __restrict__ bq, const float* __restrict__ bk, const float* __restrict__ bv,
    u16* q, u16* k, u16* vt)
{
  __shared__ char smem[147456];
  const int z = blockIdx.y;
  const u16* W = (z == 0) ? wqb : (z == 1) ? wkb : wvb;
  const float* bias = (z == 0) ? bq : (z == 1) ? bk : bv;
  const int id = blockIdx.x;                 // 0..255
  const int m0 = ((id & 7) * 4 + ((id >> 3) & 3)) * 256;   // XCD owns 4 m-tiles
  const int n0 = (id >> 5) * 128;

  f32x4 acc[4][4]; ACC_ZERO4(acc);
  gemm_256x128(xb, W, m0, n0, 16, smem, acc);

  if (z < 2) {
    store256x128_bf16(acc, bias, n0, (z == 0) ? q : k, m0, smem);
  } else {
    const int tid = threadIdx.x, lane = tid & 63, wave = tid >> 6;
    const int quad = lane >> 4, l16 = lane & 15;
    const int wr = (wave >> 1) << 6, wc = (wave & 1) << 6;
    u16* t = (u16*)smem;                     // transposed: t[n_local][m_local], 128 x 264
#pragma unroll
    for (int j = 0; j < 4; ++j) {
      const int nn = wc + j * 16 + l16;
      const float bj = bias[n0 + nn];
#pragma unroll
      for (int i = 0; i < 4; ++i) {
        const int mm = wr + i * 16 + quad * 4;
#pragma unroll
        for (int r = 0; r < 4; ++r)
          t[nn * 264 + mm + r] = f2bf(acc[i][j][r] + bj);
      }
    }
    __syncthreads();
    const int b = m0 >> 10, t0 = m0 & 1023;
#pragma unroll
    for (int it = 0; it < 8; ++it) {
      const int L = it * 512 + tid;          // 128 rows x 32 chunks of 8
      const int nn = L >> 5, cc = L & 31;
      *(uint4*)(vt + ((size_t)b << 20) + (size_t)(n0 + nn) * 1024 + t0 + cc * 8) =
          *(const uint4*)(t + nn * 264 + cc * 8);
    }
  }
}

// ---------- kernel 3: P' = exp(scale*QK^T), causal; 256x128 tiles ----------
// grid = 8 batches x 20 lower-triangle tiles (q-tile=256 rows, k-tile=128 cols)
__global__ __launch_bounds__(512, 2) void qk_exp256(
    const u16* __restrict__ q, const u16* __restrict__ k,
    u16* __restrict__ probs, float* __restrict__ rowsum)
{
  __shared__ char smem[147456];
  const int id = blockIdx.x;                 // 0..159
  const int b = id / 20;
  const int t = id - b * 20;
  const int qi = (t < 2) ? 0 : (t < 6) ? 1 : (t < 12) ? 2 : 3;
  const int pre = (qi == 0) ? 0 : (qi == 1) ? 2 : (qi == 2) ? 6 : 12;
  const int kt = t - pre;
  const int m0 = qi * 256, n0 = kt * 128;
  const u16* A = q + ((size_t)b << 20);
  const u16* B = k + ((size_t)b << 20);

  f32x4 acc[4][4]; ACC_ZERO4(acc);
  gemm_256x128(A, B, m0, n0, 16, smem, acc);

  const int tid = threadIdx.x, lane = tid & 63, wave = tid >> 6;
  const int quad = lane >> 4, l16 = lane & 15;
  const int wr = (wave >> 1) << 6, wc = (wave & 1) << 6;

  float part[4][4];
#pragma unroll
  for (int i = 0; i < 4; ++i)
#pragma unroll
    for (int r = 0; r < 4; ++r) part[i][r] = 0.f;

  u16* tl = (u16*)smem;                      // 256 x 136 u16 repack
#pragma unroll
  for (int j = 0; j < 4; ++j) {
    const int nn = wc + j * 16 + l16;
#pragma unroll
    for (int i = 0; i < 4; ++i) {
      const int mm = wr + i * 16 + quad * 4;
#pragma unroll
      for (int r = 0; r < 4; ++r) {
        float e = __expf(acc[i][j][r] * 0.03125f);
        if ((n0 + nn) > (m0 + mm + r)) e = 0.f; // causal (no-op for full tiles)
        part[i][r] += e;
        tl[(mm + r) * 136 + nn] = f2bf(e);
      }
    }
  }
  float* rs = rowsum + b * 1024 + m0;
#pragma unroll
  for (int i = 0; i < 4; ++i)
#pragma unroll
    for (int r = 0; r < 4; ++r) {
      float v = part[i][r];
      v += __shfl_xor(v, 1); v += __shfl_xor(v, 2);
      v += __shfl_xor(v, 4); v += __shfl_xor(v, 8);
      if (l16 == 0) atomicAdd(rs + wr + i * 16 + quad * 4 + r, v);
    }
  __syncthreads();
  u16* C = probs + ((size_t)b << 20);
#pragma unroll
  for (int it = 0; it < 8; ++it) {
    const int L = it * 512 + tid;            // 4096 chunks of 8 u16
    const int mm = L >> 4, cc = L & 15;
    *(uint4*)(C + (size_t)(m0 + mm) * 1024 + n0 + cc * 8) =
        *(const uint4*)(tl + mm * 136 + cc * 8);
  }
}

// ---------- kernel 4: O = diag(1/l) P' V; 256x128 tiles, variable K ----------
// grid = 256 blocks exactly: 8 batches x 4 q-tiles x 8 n-tiles
__global__ __launch_bounds__(512, 2) void pv256(
    const u16* __restrict__ probs, const u16* __restrict__ vt,
    const float* __restrict__ rowsum, u16* __restrict__ o)
{
  __shared__ char smem[147456];
  const int id = blockIdx.x;                 // 0..255
  const int b = id & 7;
  const int u = id >> 3;                     // 0..31
  const int qi = 3 - (u & 3);                // big-K blocks first
  const int nb = u >> 2;                     // 0..7
  const int m0 = qi * 256, n0 = nb * 128;
  const int nt = (qi + 1) * 4;               // K = (qi+1)*256, BK=64
  const u16* A = probs + ((size_t)b << 20);
  const u16* B = vt + ((size_t)b << 20);

  f32x4 acc[4][4]; ACC_ZERO4(acc);
  gemm_256x128(A, B, m0, n0, nt, smem, acc);

  const int tid = threadIdx.x, lane = tid & 63, wave = tid >> 6;
  const int quad = lane >> 4, l16 = lane & 15;
  const int wr = (wave >> 1) << 6, wc = (wave & 1) << 6;
  const float* rs = rowsum + b * 1024 + m0;
  u16* tl = (u16*)smem;                      // 256 x 136 u16
#pragma unroll
  for (int i = 0; i < 4; ++i)
#pragma unroll
    for (int r = 0; r < 4; ++r) {
      const int mm = wr + i * 16 + quad * 4 + r;
      const float inv = 1.0f / rs[mm];
#pragma unroll
      for (int j = 0; j < 4; ++j)
        tl[mm * 136 + wc + j * 16 + l16] = f2bf(acc[i][j][r] * inv);
    }
  __syncthreads();
  u16* C = o + ((size_t)b << 20);
#pragma unroll
  for (int it = 0; it < 8; ++it) {
    const int L = it * 512 + tid;
    const int mm = L >> 4, cc = L & 15;
    *(uint4*)(C + (size_t)(m0 + mm) * 1024 + n0 + cc * 8) =
        *(const uint4*)(tl + mm * 136 + cc * 8);
  }
}

// ---------- kernel 5: out = O Wo^T + bo; 4-phase 256x128 core, fp32 epilogue ----------
__global__ __launch_bounds__(512, 2) void proj_o(
    const u16* __restrict__ ob, const u16* __restrict__ wob,
    const float* __restrict__ bo, float* __restrict__ out)
{
  __shared__ char smem[147456];
  const int id = blockIdx.x;                 // 0..255
  const int m0 = ((id & 7) * 4 + ((id >> 3) & 3)) * 256;
  const int n0 = (id >> 5) * 128;
  f32x4 acc[4][4]; ACC_ZERO4(acc);
  gemm_256x128(ob, wob, m0, n0, 16, smem, acc);

  const int tid = threadIdx.x, lane = tid & 63, wave = tid >> 6;
  const int quad = lane >> 4, l16 = lane & 15;
  const int wr = (wave >> 1) << 6, wc = (wave & 1) << 6;
  float* tf = (float*)smem;                  // 256 x 132 fp32
#pragma unroll
  for (int j = 0; j < 4; ++j) {
    const int nn = wc + j * 16 + l16;
    const float bj = bo[n0 + nn];
#pragma unroll
    for (int i = 0; i < 4; ++i)
#pragma unroll
      for (int r = 0; r < 4; ++r)
        tf[(wr + i * 16 + quad * 4 + r) * 132 + nn] = acc[i][j][r] + bj;
  }
  __syncthreads();
#pragma unroll
  for (int it = 0; it < 16; ++it) {
    const int L = it * 512 + tid;            // 256 rows x 32 float4
    const int mm = L >> 5, cc = L & 31;
    *(float4*)(out + (size_t)(m0 + mm) * 1024 + n0 + cc * 4) =
        *(const float4*)(tf + mm * 132 + cc * 4);
  }
}

// ---------- launch ----------
extern "C" void kernel_launch(void* const* d_in, const int* in_sizes, int n_in,
                              void* d_out, int out_size, void* d_ws, size_t ws_size,
                              hipStream_t stream) {
  const float* x  = (const float*)d_in[0];
  const float* wq = (const float*)d_in[1];
  const float* bq = (const float*)d_in[2];
  const float* wk = (const float*)d_in[3];
  const float* bk = (const float*)d_in[4];
  const float* wv = (const float*)d_in[5];
  const float* bv = (const float*)d_in[6];
  const float* wo = (const float*)d_in[7];
  const float* bo = (const float*)d_in[8];
  float* out = (float*)d_out;

  char* ws = (char*)d_ws;
  const size_t MB = 1u << 20;
  u16*  xb  = (u16*)(ws);            // 16 MB (x bf16; reused later as O bf16)
  u16*  wqb = (u16*)(ws + 16*MB);
  u16*  wkb = (u16*)(ws + 18*MB);
  u16*  wvb = (u16*)(ws + 20*MB);
  u16*  wob = (u16*)(ws + 22*MB);
  u16*  qb  = (u16*)(ws + 24*MB);
  u16*  kb  = (u16*)(ws + 40*MB);
  u16*  vtb = (u16*)(ws + 56*MB);    // V transposed per batch
  u16*  pr  = (u16*)(ws + 72*MB);    // bf16 unnormalized probs P'
  float* rsum = (float*)(ws + 88*MB);// 32 KB row sums

  cast_inputs<<<6144, 256, 0, stream>>>(x, wq, wk, wv, wo, xb, wqb, wkb, wvb, wob, rsum);
  proj_qkv<<<dim3(256, 3), 512, 0, stream>>>(xb, wqb, wkb, wvb, bq, bk, bv, qb, kb, vtb);
  qk_exp256<<<160, 512, 0, stream>>>(qb, kb, pr, rsum);
  pv256<<<256, 512, 0, stream>>>(pr, vtb, rsum, xb /* O reuses x region */);
  proj_o<<<256, 512, 0, stream>>>(xb, wob, bo, out);
}

// Round 7
// 226.056 us; speedup vs baseline: 1.0126x; 1.0126x over previous
//
#include <hip/hip_runtime.h>

typedef unsigned short u16;
typedef __attribute__((ext_vector_type(8))) short short8;
typedef __attribute__((ext_vector_type(4))) float f32x4;

// ---------- helpers ----------

__device__ __forceinline__ u16 f2bf(float f) {
  unsigned u = __builtin_bit_cast(unsigned, f);
  u += 0x7fffu + ((u >> 16) & 1u);   // RNE
  return (u16)(u >> 16);
}

__device__ __forceinline__ void gload16(const void* g, void* l) {
  __builtin_amdgcn_global_load_lds(
      (const __attribute__((address_space(1))) unsigned*)g,
      (__attribute__((address_space(3))) unsigned*)l, 16, 0, 0);
}

#define MFMA16(a, b, c) __builtin_amdgcn_mfma_f32_16x16x32_bf16(a, b, c, 0, 0, 0)

// ================================================================
// CORE 1 (round-3 proven): 256x128, BK=64, 3 buffers, dist-2 prefetch,
// vmcnt(6), one barrier per K-tile. Used by qk_exp256 / pv256 / proj_o.
// ================================================================

#define PTILE(RB_C, RB_N, DOSTAGE, VM, LAST)                                  \
  {                                                                           \
    char* cA = sA0 + cur * 49152;                                             \
    /* ---- phase 0 ---- */                                                   \
    if (DOSTAGE) {                                                            \
      const int ns = (cur + 2 >= 3) ? cur - 1 : cur + 2;                      \
      char* dA = sA0 + ns * 49152;                                            \
      _Pragma("unroll") for (int j = 0; j < 3; ++j) {                         \
        gload16(ga[j], dA + la[j]); ga[j] += 64; }                            \
    }                                                                         \
    _Pragma("unroll") for (int kk = 0; kk < 2; ++kk)                          \
      _Pragma("unroll") for (int i = 0; i < 2; ++i) {                         \
        const int rm = wr + 32 + i * 16 + l16;                                \
        a1f[kk][i] = *(const short8*)(cA + rm * 128 +                         \
            (((kk << 2) + quad) ^ (rm & 7)) * 16);                            \
      }                                                                       \
    asm volatile("s_waitcnt lgkmcnt(4)" ::: "memory");                        \
    __builtin_amdgcn_sched_barrier(0);                                        \
    __builtin_amdgcn_s_setprio(1);                                            \
    _Pragma("unroll") for (int kk = 0; kk < 2; ++kk)                          \
      _Pragma("unroll") for (int i = 0; i < 2; ++i)                           \
        _Pragma("unroll") for (int j = 0; j < 4; ++j)                         \
          acc[i][j] = MFMA16(a0f[kk][i], RB_C[kk][j], acc[i][j]);             \
    __builtin_amdgcn_s_setprio(0);                                            \
    /* ---- phase 1 ---- */                                                   \
    if (DOSTAGE) {                                                            \
      const int ns = (cur + 2 >= 3) ? cur - 1 : cur + 2;                      \
      char* dA = sA0 + ns * 49152; char* dB = dA + 32768;                     \
      gload16(ga[3], dA + la[3]); ga[3] += 64;                                \
      _Pragma("unroll") for (int j = 0; j < 2; ++j) {                         \
        gload16(gb[j], dB + lb[j]); gb[j] += 64; }                            \
    }                                                                         \
    if (!(LAST)) {                                                            \
      asm volatile("s_waitcnt vmcnt(" #VM ") lgkmcnt(0)" ::: "memory");       \
      __builtin_amdgcn_s_barrier();                                           \
      asm volatile("" ::: "memory");                                          \
      const int nc = (cur + 1 >= 3) ? 0 : cur + 1;                            \
      char* nA = sA0 + nc * 49152; char* nB = nA + 32768;                     \
      _Pragma("unroll") for (int kk = 0; kk < 2; ++kk)                        \
        _Pragma("unroll") for (int j = 0; j < 4; ++j) {                       \
          const int rn = wc + j * 16 + l16;                                   \
          RB_N[kk][j] = *(const short8*)(nB + rn * 128 +                      \
              (((kk << 2) + quad) ^ (rn & 7)) * 16);                          \
        }                                                                     \
      _Pragma("unroll") for (int kk = 0; kk < 2; ++kk)                        \
        _Pragma("unroll") for (int i = 0; i < 2; ++i) {                       \
          const int rm = wr + i * 16 + l16;                                   \
          a0f[kk][i] = *(const short8*)(nA + rm * 128 +                       \
              (((kk << 2) + quad) ^ (rm & 7)) * 16);                          \
        }                                                                     \
    } else {                                                                  \
      asm volatile("s_waitcnt lgkmcnt(0)" ::: "memory");                      \
    }                                                                         \
    __builtin_amdgcn_sched_barrier(0);                                        \
    __builtin_amdgcn_s_setprio(1);                                            \
    _Pragma("unroll") for (int kk = 0; kk < 2; ++kk)                          \
      _Pragma("unroll") for (int i = 0; i < 2; ++i)                           \
        _Pragma("unroll") for (int j = 0; j < 4; ++j)                         \
          acc[2 + i][j] = MFMA16(a1f[kk][i], RB_C[kk][j], acc[2 + i][j]);     \
    __builtin_amdgcn_s_setprio(0);                                            \
    cur = (cur + 1 >= 3) ? 0 : cur + 1;                                       \
  }

__device__ __forceinline__ void gemm_256x128(
    const u16* __restrict__ A, const u16* __restrict__ B,
    int m0, int n0, int ntiles, char* smem, f32x4 acc[4][4])
{
  const int tid  = threadIdx.x;          // 0..511
  const int lane = tid & 63;
  const int quad = lane >> 4;
  const int l16  = lane & 15;
  const int wave = tid >> 6;             // 0..7
  const int wr   = (wave >> 1) << 6;     // 0,64,128,192
  const int wc   = (wave & 1) << 6;      // 0,64

  const u16* ga[4]; int la[4];
  const u16* gb[2]; int lb[2];
#pragma unroll
  for (int j = 0; j < 4; ++j) {
    const int L = j * 512 + tid;         // 2048 chunks: 256 rows x 8
    const int r = L >> 3;
    const int c = (L & 7) ^ (r & 7);
    la[j] = L * 16;
    ga[j] = A + (size_t)(m0 + r) * 1024 + c * 8;
  }
#pragma unroll
  for (int j = 0; j < 2; ++j) {
    const int L = j * 512 + tid;         // 1024 chunks: 128 rows x 8
    const int r = L >> 3;
    const int c = (L & 7) ^ (r & 7);
    lb[j] = L * 16;
    gb[j] = B + (size_t)(n0 + r) * 1024 + c * 8;
  }
  char* const sA0 = smem;                // buf b: A at b*49152, B at +32768

  short8 bfr0[2][4], bfr1[2][4];         // B frags, double-buffered
  short8 a0f[2][2], a1f[2][2];           // A frags rows 0..31 / 32..63

  // prologue: stage tiles 0 and 1 (6 gloads each)
  {
    char* dA = sA0; char* dB = sA0 + 32768;
#pragma unroll
    for (int j = 0; j < 4; ++j) { gload16(ga[j], dA + la[j]); ga[j] += 64; }
#pragma unroll
    for (int j = 0; j < 2; ++j) { gload16(gb[j], dB + lb[j]); gb[j] += 64; }
    dA = sA0 + 49152; dB = dA + 32768;
#pragma unroll
    for (int j = 0; j < 4; ++j) { gload16(ga[j], dA + la[j]); ga[j] += 64; }
#pragma unroll
    for (int j = 0; j < 2; ++j) { gload16(gb[j], dB + lb[j]); gb[j] += 64; }
  }
  asm volatile("s_waitcnt vmcnt(6)" ::: "memory");   // tile0 done, tile1 in flight
  __builtin_amdgcn_s_barrier();
  asm volatile("" ::: "memory");
  {
    char* nA = sA0; char* nB = sA0 + 32768;
#pragma unroll
    for (int kk = 0; kk < 2; ++kk)
#pragma unroll
      for (int j = 0; j < 4; ++j) {
        const int rn = wc + j * 16 + l16;
        bfr0[kk][j] = *(const short8*)(nB + rn * 128 + (((kk << 2) + quad) ^ (rn & 7)) * 16);
      }
#pragma unroll
    for (int kk = 0; kk < 2; ++kk)
#pragma unroll
      for (int i = 0; i < 2; ++i) {
        const int rm = wr + i * 16 + l16;
        a0f[kk][i] = *(const short8*)(nA + rm * 128 + (((kk << 2) + quad) ^ (rm & 7)) * 16);
      }
  }

  int cur = 0;
  const int npair = (ntiles >> 1) - 1;
#pragma unroll 1
  for (int it = 0; it < npair; ++it) {
    PTILE(bfr0, bfr1, true, 6, false);
    PTILE(bfr1, bfr0, true, 6, false);
  }
  PTILE(bfr0, bfr1, false, 0, false);
  PTILE(bfr1, bfr0, false, 0, true);
  __syncthreads();                       // epilogue may rewrite LDS
}

// ================================================================
// CORE 2 (occupancy variant for proj_qkv): 256x128, BK=32, same PTILE
// sync template (3 slots, dist-2, counted vmcnt(3), 1 barrier/tile),
// slot = 24 KB -> 72 KB LDS -> 2 blocks/CU (16 waves). Swizzle for
// 4-chunk rows: c ^= (r>>1)&3 (2-way on frag reads = free).
// ================================================================

#define PTILE32(RB_C, RB_N, DOSTAGE, VM, LAST)                                \
  {                                                                           \
    char* cA = sA0 + cur * 24576;                                             \
    /* ---- phase 0: read A rows 32-63; stage next A; MFMA acc[0..1] ---- */  \
    if (DOSTAGE) {                                                            \
      char* dA = sA0 + ((cur + 2 >= 3) ? (cur - 1) : (cur + 2)) * 24576;      \
      gload16(ga[0], dA + la[0]); ga[0] += 32;                                \
      gload16(ga[1], dA + la[1]); ga[1] += 32;                                \
    }                                                                         \
    _Pragma("unroll") for (int i = 0; i < 2; ++i) {                           \
      const int rm = wr + 32 + i * 16 + l16;                                  \
      a1f[i] = *(const short8*)(cA + rm * 64 +                                \
          ((quad ^ ((rm >> 1) & 3)) * 16));                                   \
    }                                                                         \
    asm volatile("s_waitcnt lgkmcnt(2)" ::: "memory");                        \
    __builtin_amdgcn_sched_barrier(0);                                        \
    __builtin_amdgcn_s_setprio(1);                                            \
    _Pragma("unroll") for (int i = 0; i < 2; ++i)                             \
      _Pragma("unroll") for (int j = 0; j < 4; ++j)                           \
        acc[i][j] = MFMA16(a0f[i], RB_C[j], acc[i][j]);                       \
    __builtin_amdgcn_s_setprio(0);                                            \
    /* ---- phase 1: stage next B; bar; read next B+A0; MFMA acc[2..3] */     \
    if (DOSTAGE) {                                                            \
      char* dB = sA0 + ((cur + 2 >= 3) ? (cur - 1) : (cur + 2)) * 24576 + 16384; \
      gload16(gb0, dB + lb0); gb0 += 32;                                      \
    }                                                                         \
    if (!(LAST)) {                                                            \
      asm volatile("s_waitcnt vmcnt(" #VM ") lgkmcnt(0)" ::: "memory");       \
      __builtin_amdgcn_s_barrier();                                           \
      asm volatile("" ::: "memory");                                          \
      const int nc = (cur + 1 >= 3) ? 0 : cur + 1;                            \
      char* nA = sA0 + nc * 24576; char* nB = nA + 16384;                     \
      _Pragma("unroll") for (int j = 0; j < 4; ++j) {                         \
        const int rn = wc + j * 16 + l16;                                     \
        RB_N[j] = *(const short8*)(nB + rn * 64 +                             \
            ((quad ^ ((rn >> 1) & 3)) * 16));                                 \
      }                                                                       \
      _Pragma("unroll") for (int i = 0; i < 2; ++i) {                         \
        const int rm = wr + i * 16 + l16;                                     \
        a0f[i] = *(const short8*)(nA + rm * 64 +                              \
            ((quad ^ ((rm >> 1) & 3)) * 16));                                 \
      }                                                                       \
    } else {                                                                  \
      asm volatile("s_waitcnt lgkmcnt(0)" ::: "memory");                      \
    }                                                                         \
    __builtin_amdgcn_sched_barrier(0);                                        \
    __builtin_amdgcn_s_setprio(1);                                            \
    _Pragma("unroll") for (int i = 0; i < 2; ++i)                             \
      _Pragma("unroll") for (int j = 0; j < 4; ++j)                           \
        acc[2 + i][j] = MFMA16(a1f[i], RB_C[j], acc[2 + i][j]);               \
    __builtin_amdgcn_s_setprio(0);                                            \
    cur = (cur + 1 >= 3) ? 0 : cur + 1;                                       \
  }

__device__ __forceinline__ void gemm_256x128_b32(
    const u16* __restrict__ A, const u16* __restrict__ B,
    int m0, int n0, char* smem, f32x4 acc[4][4])   // K = 1024 -> 32 tiles
{
  const int tid  = threadIdx.x;          // 0..511
  const int lane = tid & 63;
  const int quad = lane >> 4;
  const int l16  = lane & 15;
  const int wave = tid >> 6;             // 0..7
  const int wr   = (wave >> 1) << 6;     // 0,64,128,192
  const int wc   = (wave & 1) << 6;      // 0,64

  // staging: A 1024 chunks (256 rows x 4), B 512 chunks (128 rows x 4)
  const u16* ga[2]; int la[2];
  const u16* gb0;   int lb0;
#pragma unroll
  for (int j = 0; j < 2; ++j) {
    const int L = j * 512 + tid;
    const int r = L >> 2;
    const int c = (L & 3) ^ ((r >> 1) & 3);
    la[j] = L * 16;
    ga[j] = A + (size_t)(m0 + r) * 1024 + c * 8;
  }
  {
    const int r = tid >> 2;
    const int c = (tid & 3) ^ ((r >> 1) & 3);
    lb0 = tid * 16;
    gb0 = B + (size_t)(n0 + r) * 1024 + c * 8;
  }
  char* const sA0 = smem;                // slot s: A at s*24576, B at +16384

  short8 bfr0[4], bfr1[4];               // B frags, reg double-buffered
  short8 a0f[2], a1f[2];                 // A frags rows 0-31 / 32-63

  // prologue: stage tiles 0 and 1 (3 gloads each)
  {
    char* dA = sA0; char* dB = sA0 + 16384;
#pragma unroll
    for (int j = 0; j < 2; ++j) { gload16(ga[j], dA + la[j]); ga[j] += 32; }
    gload16(gb0, dB + lb0); gb0 += 32;
    dA = sA0 + 24576; dB = dA + 16384;
#pragma unroll
    for (int j = 0; j < 2; ++j) { gload16(ga[j], dA + la[j]); ga[j] += 32; }
    gload16(gb0, dB + lb0); gb0 += 32;
  }
  asm volatile("s_waitcnt vmcnt(3)" ::: "memory");   // tile0 done, tile1 in flight
  __builtin_amdgcn_s_barrier();
  asm volatile("" ::: "memory");
  // pre-read tile0's B + A0 (6 ds_reads; drained by first PTILE32's lgkm(2))
  {
    char* nA = sA0; char* nB = sA0 + 16384;
#pragma unroll
    for (int j = 0; j < 4; ++j) {
      const int rn = wc + j * 16 + l16;
      bfr0[j] = *(const short8*)(nB + rn * 64 + ((quad ^ ((rn >> 1) & 3)) * 16));
    }
#pragma unroll
    for (int i = 0; i < 2; ++i) {
      const int rm = wr + i * 16 + l16;
      a0f[i] = *(const short8*)(nA + rm * 64 + ((quad ^ ((rm >> 1) & 3)) * 16));
    }
  }

  int cur = 0;
#pragma unroll 1
  for (int it = 0; it < 15; ++it) {      // 30 staged tiles (stage t+2)
    PTILE32(bfr0, bfr1, true, 3, false);
    PTILE32(bfr1, bfr0, true, 3, false);
  }
  PTILE32(bfr0, bfr1, false, 0, false);  // tile 30: drain tile31's loads
  PTILE32(bfr1, bfr0, false, 0, true);   // tile 31
  __syncthreads();                       // epilogue may rewrite LDS
}

#define ACC_ZERO4(acc) { _Pragma("unroll") for (int i=0;i<4;++i) \
  _Pragma("unroll") for (int j=0;j<4;++j) \
  _Pragma("unroll") for (int r=0;r<4;++r) acc[i][j][r]=0.f; }

// ---------- epilogue: 256x128 acc(+bias) -> bf16 C via LDS repack ----------
__device__ __forceinline__ void store256x128_bf16(
    f32x4 acc[4][4], const float* bias, int n0,
    u16* C, int m0, char* smem)
{
  const int tid = threadIdx.x, lane = tid & 63, wave = tid >> 6;
  const int quad = lane >> 4, l16 = lane & 15;
  const int wr = (wave >> 1) << 6, wc = (wave & 1) << 6;
  u16* t = (u16*)smem;                       // 256 x 136 u16 (69632 B)
#pragma unroll
  for (int j = 0; j < 4; ++j) {
    const int nn = wc + j * 16 + l16;
    const float bj = bias[n0 + nn];
#pragma unroll
    for (int i = 0; i < 4; ++i) {
      const int mm = wr + i * 16 + quad * 4;
#pragma unroll
      for (int r = 0; r < 4; ++r)
        t[(mm + r) * 136 + nn] = f2bf(acc[i][j][r] + bj);
    }
  }
  __syncthreads();
#pragma unroll
  for (int it = 0; it < 8; ++it) {
    const int L = it * 512 + tid;              // 4096 chunks of 8 u16
    const int mm = L >> 4, cc = L & 15;
    *(uint4*)(C + (size_t)(m0 + mm) * 1024 + n0 + cc * 8) =
        *(const uint4*)(t + mm * 136 + cc * 8);
  }
}

// ---------- kernel 1: cast fp32 -> bf16 (x + 4 weights) + zero rowsum ----------
__global__ __launch_bounds__(256) void cast_inputs(
    const float* __restrict__ x,  const float* __restrict__ wq,
    const float* __restrict__ wk, const float* __restrict__ wv,
    const float* __restrict__ wo,
    u16* xb, u16* wqb, u16* wkb, u16* wvb, u16* wob, float* rsum)
{
  int b = blockIdx.x;
  if (b < 8) {                               // fold rowsum zeroing (8192 floats)
    float4 z = {0.f, 0.f, 0.f, 0.f};
    *(float4*)(rsum + (b * 256 + threadIdx.x) * 4) = z;
  }
  const float* src; u16* dst; int base;
  if (b < 4096) { src = x; dst = xb; base = b * 2048; }
  else {
    int r = (b - 4096) >> 9, bb = (b - 4096) & 511;
    base = bb * 2048;
    src = (r == 0) ? wq : (r == 1) ? wk : (r == 2) ? wv : wo;
    dst = (r == 0) ? wqb : (r == 1) ? wkb : (r == 2) ? wvb : wob;
  }
  int i0 = base + threadIdx.x * 8;
  float4 f0 = *(const float4*)(src + i0);
  float4 f1 = *(const float4*)(src + i0 + 4);
  short8 o;
  o[0]=(short)f2bf(f0.x); o[1]=(short)f2bf(f0.y); o[2]=(short)f2bf(f0.z); o[3]=(short)f2bf(f0.w);
  o[4]=(short)f2bf(f1.x); o[5]=(short)f2bf(f1.y); o[6]=(short)f2bf(f1.z); o[7]=(short)f2bf(f1.w);
  *(short8*)(dst + i0) = o;
}

// ---------- kernel 2: fused QKV projection, BK=32 core, 2 blocks/CU ----------
// grid (256, 3): x = XCD-chunked tile id, y = which weight (q/k/v).
// 512 threads, 72 KiB LDS -> 2 blocks/CU (16 waves): barrier stalls of one
// block overlap the other block's MFMA (m114 mechanism).
__global__ __launch_bounds__(512, 4) void proj_qkv(
    const u16* __restrict__ xb,
    const u16* __restrict__ wqb, const u16* __restrict__ wkb, const u16* __restrict__ wvb,
    const float* __restrict__ bq, const float* __restrict__ bk, const float* __restrict__ bv,
    u16* q, u16* k, u16* vt)
{
  __shared__ char smem[73728];               // 3 x 24576; epi needs 69632
  const int z = blockIdx.y;
  const u16* W = (z == 0) ? wqb : (z == 1) ? wkb : wvb;
  const float* bias = (z == 0) ? bq : (z == 1) ? bk : bv;
  const int id = blockIdx.x;                 // 0..255
  const int m0 = ((id & 7) * 4 + ((id >> 3) & 3)) * 256;   // XCD owns 4 m-tiles
  const int n0 = (id >> 5) * 128;

  f32x4 acc[4][4]; ACC_ZERO4(acc);
  gemm_256x128_b32(xb, W, m0, n0, smem, acc);

  if (z < 2) {
    store256x128_bf16(acc, bias, n0, (z == 0) ? q : k, m0, smem);
  } else {
    const int tid = threadIdx.x, lane = tid & 63, wave = tid >> 6;
    const int quad = lane >> 4, l16 = lane & 15;
    const int wr = (wave >> 1) << 6, wc = (wave & 1) << 6;
    u16* t = (u16*)smem;                     // transposed: 128 x 264 u16 (67584 B)
#pragma unroll
    for (int j = 0; j < 4; ++j) {
      const int nn = wc + j * 16 + l16;
      const float bj = bias[n0 + nn];
#pragma unroll
      for (int i = 0; i < 4; ++i) {
        const int mm = wr + i * 16 + quad * 4;
#pragma unroll
        for (int r = 0; r < 4; ++r)
          t[nn * 264 + mm + r] = f2bf(acc[i][j][r] + bj);
      }
    }
    __syncthreads();
    const int b = m0 >> 10, t0 = m0 & 1023;
#pragma unroll
    for (int it = 0; it < 8; ++it) {
      const int L = it * 512 + tid;          // 128 rows x 32 chunks of 8
      const int nn = L >> 5, cc = L & 31;
      *(uint4*)(vt + ((size_t)b << 20) + (size_t)(n0 + nn) * 1024 + t0 + cc * 8) =
          *(const uint4*)(t + nn * 264 + cc * 8);
    }
  }
}

// ---------- kernel 3: P' = exp(scale*QK^T), causal; 256x128 tiles ----------
// grid = 8 batches x 20 lower-triangle tiles (q-tile=256 rows, k-tile=128 cols)
__global__ __launch_bounds__(512, 2) void qk_exp256(
    const u16* __restrict__ q, const u16* __restrict__ k,
    u16* __restrict__ probs, float* __restrict__ rowsum)
{
  __shared__ char smem[147456];
  const int id = blockIdx.x;                 // 0..159
  const int b = id / 20;
  const int t = id - b * 20;
  const int qi = (t < 2) ? 0 : (t < 6) ? 1 : (t < 12) ? 2 : 3;
  const int pre = (qi == 0) ? 0 : (qi == 1) ? 2 : (qi == 2) ? 6 : 12;
  const int kt = t - pre;
  const int m0 = qi * 256, n0 = kt * 128;
  const u16* A = q + ((size_t)b << 20);
  const u16* B = k + ((size_t)b << 20);

  f32x4 acc[4][4]; ACC_ZERO4(acc);
  gemm_256x128(A, B, m0, n0, 16, smem, acc);

  const int tid = threadIdx.x, lane = tid & 63, wave = tid >> 6;
  const int quad = lane >> 4, l16 = lane & 15;
  const int wr = (wave >> 1) << 6, wc = (wave & 1) << 6;

  float part[4][4];
#pragma unroll
  for (int i = 0; i < 4; ++i)
#pragma unroll
    for (int r = 0; r < 4; ++r) part[i][r] = 0.f;

  u16* tl = (u16*)smem;                      // 256 x 136 u16 repack
#pragma unroll
  for (int j = 0; j < 4; ++j) {
    const int nn = wc + j * 16 + l16;
#pragma unroll
    for (int i = 0; i < 4; ++i) {
      const int mm = wr + i * 16 + quad * 4;
#pragma unroll
      for (int r = 0; r < 4; ++r) {
        float e = __expf(acc[i][j][r] * 0.03125f);
        if ((n0 + nn) > (m0 + mm + r)) e = 0.f; // causal (no-op for full tiles)
        part[i][r] += e;
        tl[(mm + r) * 136 + nn] = f2bf(e);
      }
    }
  }
  float* rs = rowsum + b * 1024 + m0;
#pragma unroll
  for (int i = 0; i < 4; ++i)
#pragma unroll
    for (int r = 0; r < 4; ++r) {
      float v = part[i][r];
      v += __shfl_xor(v, 1); v += __shfl_xor(v, 2);
      v += __shfl_xor(v, 4); v += __shfl_xor(v, 8);
      if (l16 == 0) atomicAdd(rs + wr + i * 16 + quad * 4 + r, v);
    }
  __syncthreads();
  u16* C = probs + ((size_t)b << 20);
#pragma unroll
  for (int it = 0; it < 8; ++it) {
    const int L = it * 512 + tid;            // 4096 chunks of 8 u16
    const int mm = L >> 4, cc = L & 15;
    *(uint4*)(C + (size_t)(m0 + mm) * 1024 + n0 + cc * 8) =
        *(const uint4*)(tl + mm * 136 + cc * 8);
  }
}

// ---------- kernel 4: O = diag(1/l) P' V; 256x128 tiles, variable K ----------
// grid = 256 blocks exactly: 8 batches x 4 q-tiles x 8 n-tiles
__global__ __launch_bounds__(512, 2) void pv256(
    const u16* __restrict__ probs, const u16* __restrict__ vt,
    const float* __restrict__ rowsum, u16* __restrict__ o)
{
  __shared__ char smem[147456];
  const int id = blockIdx.x;                 // 0..255
  const int b = id & 7;
  const int u = id >> 3;                     // 0..31
  const int qi = 3 - (u & 3);                // big-K blocks first
  const int nb = u >> 2;                     // 0..7
  const int m0 = qi * 256, n0 = nb * 128;
  const int nt = (qi + 1) * 4;               // K = (qi+1)*256, BK=64
  const u16* A = probs + ((size_t)b << 20);
  const u16* B = vt + ((size_t)b << 20);

  f32x4 acc[4][4]; ACC_ZERO4(acc);
  gemm_256x128(A, B, m0, n0, nt, smem, acc);

  const int tid = threadIdx.x, lane = tid & 63, wave = tid >> 6;
  const int quad = lane >> 4, l16 = lane & 15;
  const int wr = (wave >> 1) << 6, wc = (wave & 1) << 6;
  const float* rs = rowsum + b * 1024 + m0;
  u16* tl = (u16*)smem;                      // 256 x 136 u16
#pragma unroll
  for (int i = 0; i < 4; ++i)
#pragma unroll
    for (int r = 0; r < 4; ++r) {
      const int mm = wr + i * 16 + quad * 4 + r;
      const float inv = 1.0f / rs[mm];
#pragma unroll
      for (int j = 0; j < 4; ++j)
        tl[mm * 136 + wc + j * 16 + l16] = f2bf(acc[i][j][r] * inv);
    }
  __syncthreads();
  u16* C = o + ((size_t)b << 20);
#pragma unroll
  for (int it = 0; it < 8; ++it) {
    const int L = it * 512 + tid;
    const int mm = L >> 4, cc = L & 15;
    *(uint4*)(C + (size_t)(m0 + mm) * 1024 + n0 + cc * 8) =
        *(const uint4*)(tl + mm * 136 + cc * 8);
  }
}

// ---------- kernel 5: out = O Wo^T + bo; BK=64 core, fp32 epilogue ----------
__global__ __launch_bounds__(512, 2) void proj_o(
    const u16* __restrict__ ob, const u16* __restrict__ wob,
    const float* __restrict__ bo, float* __restrict__ out)
{
  __shared__ char smem[147456];
  const int id = blockIdx.x;                 // 0..255
  const int m0 = ((id & 7) * 4 + ((id >> 3) & 3)) * 256;
  const int n0 = (id >> 5) * 128;
  f32x4 acc[4][4]; ACC_ZERO4(acc);
  gemm_256x128(ob, wob, m0, n0, 16, smem, acc);

  const int tid = threadIdx.x, lane = tid & 63, wave = tid >> 6;
  const int quad = lane >> 4, l16 = lane & 15;
  const int wr = (wave >> 1) << 6, wc = (wave & 1) << 6;
  float* tf = (float*)smem;                  // 256 x 132 fp32
#pragma unroll
  for (int j = 0; j < 4; ++j) {
    const int nn = wc + j * 16 + l16;
    const float bj = bo[n0 + nn];
#pragma unroll
    for (int i = 0; i < 4; ++i)
#pragma unroll
      for (int r = 0; r < 4; ++r)
        tf[(wr + i * 16 + quad * 4 + r) * 132 + nn] = acc[i][j][r] + bj;
  }
  __syncthreads();
#pragma unroll
  for (int it = 0; it < 16; ++it) {
    const int L = it * 512 + tid;            // 256 rows x 32 float4
    const int mm = L >> 5, cc = L & 31;
    *(float4*)(out + (size_t)(m0 + mm) * 1024 + n0 + cc * 4) =
        *(const float4*)(tf + mm * 132 + cc * 4);
  }
}

// ---------- launch ----------
extern "C" void kernel_launch(void* const* d_in, const int* in_sizes, int n_in,
                              void* d_out, int out_size, void* d_ws, size_t ws_size,
                              hipStream_t stream) {
  const float* x  = (const float*)d_in[0];
  const float* wq = (const float*)d_in[1];
  const float* bq = (const float*)d_in[2];
  const float* wk = (const float*)d_in[3];
  const float* bk = (const float*)d_in[4];
  const float* wv = (const float*)d_in[5];
  const float* bv = (const float*)d_in[6];
  const float* wo = (const float*)d_in[7];
  const float* bo = (const float*)d_in[8];
  float* out = (float*)d_out;

  char* ws = (char*)d_ws;
  const size_t MB = 1u << 20;
  u16*  xb  = (u16*)(ws);            // 16 MB (x bf16; reused later as O bf16)
  u16*  wqb = (u16*)(ws + 16*MB);
  u16*  wkb = (u16*)(ws + 18*MB);
  u16*  wvb = (u16*)(ws + 20*MB);
  u16*  wob = (u16*)(ws + 22*MB);
  u16*  qb  = (u16*)(ws + 24*MB);
  u16*  kb  = (u16*)(ws + 40*MB);
  u16*  vtb = (u16*)(ws + 56*MB);    // V transposed per batch
  u16*  pr  = (u16*)(ws + 72*MB);    // bf16 unnormalized probs P'
  float* rsum = (float*)(ws + 88*MB);// 32 KB row sums

  cast_inputs<<<6144, 256, 0, stream>>>(x, wq, wk, wv, wo, xb, wqb, wkb, wvb, wob, rsum);
  proj_qkv<<<dim3(256, 3), 512, 0, stream>>>(xb, wqb, wkb, wvb, bq, bk, bv, qb, kb, vtb);
  qk_exp256<<<160, 512, 0, stream>>>(qb, kb, pr, rsum);
  pv256<<<256, 512, 0, stream>>>(pr, vtb, rsum, xb /* O reuses x region */);
  proj_o<<<256, 512, 0, stream>>>(xb, wob, bo, out);
}